// Round 7
// baseline (811.661 us; speedup 1.0000x reference)
//
#include <hip/hip_runtime.h>
#include <math.h>

// Problem constants
#define B_   16
#define C_   512
#define HW_  4096
#define T_   768
#define NH   12
#define DH   64
#define MT_  32          // blocks per b; m-range per block = 128
#define MRANGE 128
#define SW   16          // subtile width (m)
#define NSUB 8           // MRANGE / SW
#define XSTR 516         // xT row stride (floats): 516 % 32 = 4 -> 2-way patterns

typedef float nfloat4 __attribute__((ext_vector_type(4)));

// Workspace layout (floats):
//   qkT   @ 0        [B][C][NH]        98304
//   pd    @ 98304    [MT][B][NH]       6144
//   ypart @ 104448   [MT][B][NH][C]    3145728
//   y     @ 3250176  [B][NH][C]        98304
//   outT  @ 3348480  [B][T]            12288

// ---------------------------------------------------------------------------
// Kernel A: qkT[b][c][h] = (1/8) * sum_dd t[b, h*64+dd] * Wk[h*64+dd, c]
__global__ __launch_bounds__(512) void qk_kernel(
    const float* __restrict__ t, const float* __restrict__ Wk,
    float* __restrict__ qkT) {
  int bh = blockIdx.x;
  int b = bh / NH, h = bh % NH;
  __shared__ float tl[DH];
  int tid = threadIdx.x;
  if (tid < DH) tl[tid] = t[b * T_ + h * DH + tid];
  __syncthreads();
  int c = tid;
  float acc = 0.f;
#pragma unroll
  for (int dd = 0; dd < DH; ++dd)
    acc += tl[dd] * Wk[(h * DH + dd) * C_ + c];
  qkT[((size_t)b * C_ + c) * NH + h] = acc * 0.125f;
}

// ---------------------------------------------------------------------------
// Kernel B (flash v3): block (mt,b) owns 128 m in 8 subtiles of 16.
// Register-lean score (sp[24]); q from L2; xT [m][c] staged for PV;
// all LDS patterns <=2-way; LDS 44.3 KB -> target 3 blocks/CU.
__global__ __launch_bounds__(512, 6) void flash_kernel(
    const float* __restrict__ x, const float* __restrict__ qkT,
    float* __restrict__ pd, float* __restrict__ ypart) {
  int mt = blockIdx.x;   // 0..31
  int b  = blockIdx.y;   // 0..15
  int tid = threadIdx.x; // 0..511

  __shared__ __align__(16) float xT[SW][XSTR];       // 33024 B
  __shared__ __align__(16) float Plds[NH][MRANGE];   // 6144 B
  __shared__ __align__(16) float red[8][8][24];      // 6144 B
  // total 44.3 KB

  const int scs_l = tid & 7;          // in-wave c-split (lane bits 0-2)
  const int sm8   = (tid >> 3) & 7;   // m-pair slot     (lane bits 3-5)
  const int w     = tid >> 6;         // wave
  const int scs   = w * 8 + scs_l;    // global c-split 0..63 (8 c each)
  const int mbase = mt * MRANGE;
  const int c1    = tid;              // PV column
  const bool s2   = (tid < 192);      // stage-2 threads (3 full waves)
  const int s2m   = tid & 15, s2h = tid >> 4;

  float accy[NH];
#pragma unroll
  for (int h = 0; h < NH; ++h) accy[h] = 0.f;
  float pdacc = 0.f;

  const float* qb_base = qkT + (size_t)b * C_ * NH;
  const float* xb_base = x + (size_t)b * C_ * HW_ + mbase;

  for (int ms = 0; ms < NSUB; ++ms) {
    // ---- 1. load this subtile's x into registers (rotated c-order so the
    //         later xT writes are 2-way; rotation at ADDRESS, reg idx static)
    float2 xr[8];
#pragma unroll
    for (int k = 0; k < 8; ++k) {
      int ck = scs * 8 + ((k + sm8) & 7);
      xr[k] = *(const float2*)(xb_base + (size_t)ck * HW_ + ms * SW + sm8 * 2);
    }

    // ---- 2. PV of previous subtile from xT + Plds (overlaps load latency)
    if (ms > 0) {
      int mp = (ms - 1) * SW;
#pragma unroll
      for (int mq = 0; mq < 4; ++mq) {
        float xw0 = xT[mq * 4 + 0][c1];
        float xw1 = xT[mq * 4 + 1][c1];
        float xw2 = xT[mq * 4 + 2][c1];
        float xw3 = xT[mq * 4 + 3][c1];
#pragma unroll
        for (int h = 0; h < NH; ++h) {
          float4 pb = *(const float4*)&Plds[h][mp + mq * 4];
          accy[h] += pb.x * xw0 + pb.y * xw1 + pb.z * xw2 + pb.w * xw3;
        }
      }
    }
    __syncthreads();  // (a) PV done -> xT writable

    // ---- 3. score + xT stage. sp[h*2+mm], 24 accumulators.
    float sp[24];
#pragma unroll
    for (int j = 0; j < 24; ++j) sp[j] = 0.f;
#pragma unroll
    for (int k = 0; k < 8; ++k) {
      int ck = scs * 8 + ((k + sm8) & 7);
      const float* qr = qb_base + (size_t)ck * NH;
      float4 q0 = *(const float4*)(qr);
      float4 q1 = *(const float4*)(qr + 4);
      float4 q2 = *(const float4*)(qr + 8);
      float2 v = xr[k];
      sp[0]  += q0.x * v.x; sp[1]  += q0.x * v.y;
      sp[2]  += q0.y * v.x; sp[3]  += q0.y * v.y;
      sp[4]  += q0.z * v.x; sp[5]  += q0.z * v.y;
      sp[6]  += q0.w * v.x; sp[7]  += q0.w * v.y;
      sp[8]  += q1.x * v.x; sp[9]  += q1.x * v.y;
      sp[10] += q1.y * v.x; sp[11] += q1.y * v.y;
      sp[12] += q1.z * v.x; sp[13] += q1.z * v.y;
      sp[14] += q1.w * v.x; sp[15] += q1.w * v.y;
      sp[16] += q2.x * v.x; sp[17] += q2.x * v.y;
      sp[18] += q2.y * v.x; sp[19] += q2.y * v.y;
      sp[20] += q2.z * v.x; sp[21] += q2.z * v.y;
      sp[22] += q2.w * v.x; sp[23] += q2.w * v.y;
      // stage to xT (2-way banks thanks to rotation)
      xT[sm8 * 2 + 0][ck] = v.x;
      xT[sm8 * 2 + 1][ck] = v.y;
    }

    // ---- 4. reduce over the 8 in-wave c-splits (bits 0-2: quad+quad+1 LDS)
#pragma unroll
    for (int j = 0; j < 24; ++j) {
      float v = sp[j];
      v += __shfl_xor(v, 1);
      v += __shfl_xor(v, 2);
      v += __shfl_xor(v, 4);
      sp[j] = v;
    }
    if (scs_l == 0) {
#pragma unroll
      for (int q = 0; q < 6; ++q) {
        float4 t4;
        t4.x = sp[q * 4 + 0]; t4.y = sp[q * 4 + 1];
        t4.z = sp[q * 4 + 2]; t4.w = sp[q * 4 + 3];
        *(float4*)&red[w][sm8][q * 4] = t4;
      }
    }
    __syncthreads();  // (b) red + xT ready

    // ---- 5. stage-2: sum 8 waves, exp, publish P; partial denominators
    if (s2) {
      float s = 0.f;
#pragma unroll
      for (int w2 = 0; w2 < 8; ++w2)
        s += red[w2][s2m >> 1][s2h * 2 + (s2m & 1)];
      float p = __expf(s);
      Plds[s2h][ms * SW + s2m] = p;
      float ps = p;
      ps += __shfl_xor(ps, 1);
      ps += __shfl_xor(ps, 2);
      ps += __shfl_xor(ps, 4);
      ps += __shfl_xor(ps, 8);
      pdacc += ps;   // sum over 16 m of this subtile (uniform per h-group)
    }
    __syncthreads();  // (c) P ready
  }

  // ---- PV for the last subtile
  {
    int mp = (NSUB - 1) * SW;
#pragma unroll
    for (int mq = 0; mq < 4; ++mq) {
      float xw0 = xT[mq * 4 + 0][c1];
      float xw1 = xT[mq * 4 + 1][c1];
      float xw2 = xT[mq * 4 + 2][c1];
      float xw3 = xT[mq * 4 + 3][c1];
#pragma unroll
      for (int h = 0; h < NH; ++h) {
        float4 pb = *(const float4*)&Plds[h][mp + mq * 4];
        accy[h] += pb.x * xw0 + pb.y * xw1 + pb.z * xw2 + pb.w * xw3;
      }
    }
  }

  // partial denominators
  if (s2 && (s2m == 0))
    pd[((size_t)mt * B_ + b) * NH + s2h] = pdacc;

  // ypart[mt][b][h][c] (coalesced per h)
  float* yp = ypart + ((size_t)mt * B_ + b) * NH * C_;
#pragma unroll
  for (int h = 0; h < NH; ++h) yp[h * C_ + c1] = accy[h];
}

// ---------------------------------------------------------------------------
// Kernel C (combine): y[b][h][c] = (sum_mt ypart) / (sum_mt pd)
__global__ __launch_bounds__(512) void combine_kernel(
    const float* __restrict__ pd, const float* __restrict__ ypart,
    float* __restrict__ y) {
  int bh = blockIdx.x;            // 0..191
  int b = bh / NH, h = bh % NH;
  int c = threadIdx.x;            // 0..511
  float denom = 0.f;
#pragma unroll
  for (int mt = 0; mt < MT_; ++mt)
    denom += pd[((size_t)mt * B_ + b) * NH + h];
  float s = 0.f;
#pragma unroll
  for (int mt = 0; mt < MT_; ++mt)
    s += ypart[(((size_t)mt * B_ + b) * NH + h) * C_ + c];
  y[((size_t)b * NH + h) * C_ + c] = s / denom;
}

// ---------------------------------------------------------------------------
// Kernel E: outT[b][t] = bv[t] + sum_c Wv[t,c] * y[b][t/64][c]
__global__ __launch_bounds__(256) void out_kernel(
    const float* __restrict__ Wv, const float* __restrict__ bv,
    const float* __restrict__ y, float* __restrict__ outT) {
  int o = blockIdx.x * 4 + (threadIdx.x >> 6);
  int lane = threadIdx.x & 63;
  int b = o / T_, t = o % T_;
  int h = t / DH;
  const float* wr = Wv + (size_t)t * C_;
  const float* yr = y + ((size_t)b * NH + h) * C_;
  float s = 0.f;
#pragma unroll
  for (int j = 0; j < 8; ++j) { int c = j * 64 + lane; s += wr[c] * yr[c]; }
  for (int off = 32; off; off >>= 1) s += __shfl_xor(s, off);
  if (lane == 0) outT[o] = s + bv[t];
}

// ---------------------------------------------------------------------------
// Kernel F (fused z+add): one warp per (b,c) plane.
__global__ __launch_bounds__(256) void zadd_kernel(
    const float* __restrict__ Wo, const float* __restrict__ bo,
    const float* __restrict__ outT, const float* __restrict__ cond,
    float* __restrict__ out) {
  int o = blockIdx.x * 4 + (threadIdx.x >> 6);  // o = b*C + c
  int lane = threadIdx.x & 63;
  int b = o / C_, c = o % C_;
  const float* wr = Wo + (size_t)c * T_;
  const float* orr = outT + (size_t)b * T_;
  float s = 0.f;
#pragma unroll
  for (int j = 0; j < 12; ++j) { int t = j * 64 + lane; s += wr[t] * orr[t]; }
  for (int off = 32; off; off >>= 1) s += __shfl_xor(s, off);
  float zv = s + bo[c];

  const nfloat4* cp = (const nfloat4*)(cond + (size_t)o * HW_);
  nfloat4* op = (nfloat4*)(out + (size_t)o * HW_);
#pragma unroll
  for (int j = 0; j < 16; ++j) {
    nfloat4 cv = __builtin_nontemporal_load(&cp[j * 64 + lane]);
    __builtin_nontemporal_store(cv + zv, &op[j * 64 + lane]);
  }
}

// ---------------------------------------------------------------------------
extern "C" void kernel_launch(void* const* d_in, const int* in_sizes, int n_in,
                              void* d_out, int out_size, void* d_ws, size_t ws_size,
                              hipStream_t stream) {
  const float* cond = (const float*)d_in[0];
  const float* t    = (const float*)d_in[1];
  const float* Wk   = (const float*)d_in[2];
  // bk (d_in[3]) unused: bias cancels in softmax
  const float* Wv   = (const float*)d_in[4];
  const float* bv   = (const float*)d_in[5];
  const float* Wo   = (const float*)d_in[6];
  const float* bo   = (const float*)d_in[7];
  float* out = (float*)d_out;
  float* ws  = (float*)d_ws;

  float* qkT   = ws;
  float* pd    = ws + 98304;
  float* ypart = ws + 104448;
  float* y     = ws + 3250176;
  float* outT  = ws + 3348480;

  hipLaunchKernelGGL(qk_kernel, dim3(B_ * NH), dim3(512), 0, stream,
                     t, Wk, qkT);
  hipLaunchKernelGGL(flash_kernel, dim3(MT_, B_), dim3(512), 0, stream,
                     cond, qkT, pd, ypart);
  hipLaunchKernelGGL(combine_kernel, dim3(B_ * NH), dim3(512), 0, stream,
                     pd, ypart, y);
  hipLaunchKernelGGL(out_kernel, dim3((B_ * T_) / 4), dim3(256), 0, stream,
                     Wv, bv, y, outT);
  hipLaunchKernelGGL(zadd_kernel, dim3((B_ * C_) / 4), dim3(256), 0, stream,
                     Wo, bo, outT, cond, out);
}

// Round 8
// 409.076 us; speedup vs baseline: 1.9841x; 1.9841x over previous
//
#include <hip/hip_runtime.h>
#include <math.h>

// Problem constants
#define B_   16
#define C_   512
#define HW_  4096
#define T_   768
#define NH   12
#define DH   64
#define MT_  32          // blocks per b; m-range per block = 128
#define MRANGE 128
#define SW   16          // subtile width (m)
#define NSUB 8           // MRANGE / SW
#define XSTR 516         // xT row stride: 516%32=4 -> stores 4-way, PV reads conflict-free

typedef float nfloat4 __attribute__((ext_vector_type(4)));

// Workspace layout (floats):
//   qkT   @ 0        [B][C][NH]        98304
//   pd    @ 98304    [MT][B][NH]       6144
//   ypart @ 104448   [MT][B][NH][C]    3145728
//   y     @ 3250176  [B][NH][C]        98304
//   outT  @ 3348480  [B][T]            12288

// ---------------------------------------------------------------------------
// Kernel A: qkT[b][c][h] = (1/8) * sum_dd t[b, h*64+dd] * Wk[h*64+dd, c]
__global__ __launch_bounds__(512) void qk_kernel(
    const float* __restrict__ t, const float* __restrict__ Wk,
    float* __restrict__ qkT) {
  int bh = blockIdx.x;
  int b = bh / NH, h = bh % NH;
  __shared__ float tl[DH];
  int tid = threadIdx.x;
  if (tid < DH) tl[tid] = t[b * T_ + h * DH + tid];
  __syncthreads();
  int c = tid;
  float acc = 0.f;
#pragma unroll
  for (int dd = 0; dd < DH; ++dd)
    acc += tl[dd] * Wk[(h * DH + dd) * C_ + c];
  qkT[((size_t)b * C_ + c) * NH + h] = acc * 0.125f;
}

// ---------------------------------------------------------------------------
// Kernel B (flash v4): block (mt,b) owns 128 m in 8 subtiles of 16.
// Invariants enforced simultaneously (each was a prior failure):
//  - x loads: float4, m-slot in lane bits 0-1 -> 64B contiguous aligned
//    segments, zero overfetch                        (v3 failure)
//  - live regs ~95: sp[48]+xv[16]+accy[12], 4 c/thread, q via LDS [h][c]
//    (no qa unpack), launch_bounds(512,4) -> no spill (v2/v3 failure)
//  - LDS 69.9 KB -> 2 blocks/CU                      (v2 failure)
//  - LDS patterns: qlds reads 2-way, xT PV-reads conflict-free,
//    xT stores 4-way, P-reads broadcast               (v1/v2 failure)
__global__ __launch_bounds__(512, 4) void flash_kernel(
    const float* __restrict__ x, const float* __restrict__ qkT,
    float* __restrict__ pd, float* __restrict__ ypart) {
  int mt = blockIdx.x;   // 0..31
  int b  = blockIdx.y;   // 0..15
  int tid = threadIdx.x; // 0..511

  __shared__ __align__(16) float qlds[NH][C_];      // 24576 B, [h][c]
  __shared__ __align__(16) float xT[SW][XSTR];      // 33024 B
  __shared__ __align__(16) float Plds[NH][MRANGE];  // 6144 B
  __shared__ __align__(16) float red[8][4][48];     // 6144 B
  // total 69.9 KB -> 2 blocks/CU

  // transpose-stage q once: qlds[h][c] = qkT[b][c][h]
  {
    const float* qsrc = qkT + (size_t)b * C_ * NH;
    for (int idx = tid; idx < C_ * NH; idx += 512) {
      int c = idx / NH, h = idx - c * NH;
      qlds[h][c] = qsrc[idx];
    }
  }

  const int m4 = tid & 3;    // m-slot: lane bits 0-1 -> 4 lanes x 16B = 64B runs
  const int cs = tid >> 2;   // 0..127, 4 consecutive c-rows each
  const int w  = tid >> 6;   // wave
  const int mbase = mt * MRANGE;
  const int c1 = tid;        // PV column
  const bool s2 = (tid < 192);

  float accy[NH];
#pragma unroll
  for (int h = 0; h < NH; ++h) accy[h] = 0.f;
  float pdacc = 0.f;

  const float* xp0 = x + ((size_t)b * C_ + cs * 4) * HW_ + mbase + m4 * 4;

  for (int ms = 0; ms < NSUB; ++ms) {
    // ---- 1. coalesced loads: 4 c-rows x float4
    float4 xv[4];
#pragma unroll
    for (int i = 0; i < 4; ++i)
      xv[i] = *(const float4*)(xp0 + (size_t)i * HW_ + ms * SW);

    // ---- 2. PV of previous subtile (overlaps load latency)
    if (ms > 0) {
      int mp = (ms - 1) * SW;
#pragma unroll
      for (int mq = 0; mq < 4; ++mq) {
        float xw0 = xT[mq * 4 + 0][c1];
        float xw1 = xT[mq * 4 + 1][c1];
        float xw2 = xT[mq * 4 + 2][c1];
        float xw3 = xT[mq * 4 + 3][c1];
#pragma unroll
        for (int h = 0; h < NH; ++h) {
          float4 pb = *(const float4*)&Plds[h][mp + mq * 4];
          accy[h] += pb.x * xw0 + pb.y * xw1 + pb.z * xw2 + pb.w * xw3;
        }
      }
    }
    __syncthreads();  // (a) xT writable; qlds staged (ms==0)

    // ---- 3. score partials + xT stage
    float sp[48];
#pragma unroll
    for (int j = 0; j < 48; ++j) sp[j] = 0.f;
#pragma unroll
    for (int i = 0; i < 4; ++i) {
      int c = cs * 4 + i;
      float4 v = xv[i];
#pragma unroll
      for (int h = 0; h < NH; ++h) {
        float qv = qlds[h][c];
        sp[h * 4 + 0] += qv * v.x;
        sp[h * 4 + 1] += qv * v.y;
        sp[h * 4 + 2] += qv * v.z;
        sp[h * 4 + 3] += qv * v.w;
      }
      xT[m4 * 4 + 0][c] = v.x;
      xT[m4 * 4 + 1][c] = v.y;
      xT[m4 * 4 + 2][c] = v.z;
      xT[m4 * 4 + 3][c] = v.w;
    }

    // ---- 4. in-wave reduce over 16 c-splits (lane bits 2-5)
#pragma unroll
    for (int j = 0; j < 48; ++j) {
      float v = sp[j];
      v += __shfl_xor(v, 4);
      v += __shfl_xor(v, 8);
      v += __shfl_xor(v, 16);
      v += __shfl_xor(v, 32);
      sp[j] = v;
    }
    if ((tid & 60) == 0) {  // lanes 0-3 of each wave (lane == m4)
#pragma unroll
      for (int q = 0; q < 12; ++q) {
        float4 t4;
        t4.x = sp[q * 4 + 0]; t4.y = sp[q * 4 + 1];
        t4.z = sp[q * 4 + 2]; t4.w = sp[q * 4 + 3];
        *(float4*)&red[w][m4][q * 4] = t4;
      }
    }
    __syncthreads();  // (b) red + xT ready

    // ---- 5. stage-2: sum 8 waves -> exp -> P; accumulate denominators
    if (s2) {
      int h = tid >> 4, j = (tid >> 2) & 3, mm = tid & 3;
      float s = 0.f;
#pragma unroll
      for (int w2 = 0; w2 < 8; ++w2) s += red[w2][mm][h * 4 + j];
      float p = __expf(s);
      Plds[h][ms * SW + mm * 4 + j] = p;
      float ps = p;
      ps += __shfl_xor(ps, 1);
      ps += __shfl_xor(ps, 2);
      ps += __shfl_xor(ps, 4);
      ps += __shfl_xor(ps, 8);
      pdacc += ps;  // full-subtile sum, valid on lanes with (tid&15)==0
    }
    __syncthreads();  // (c) P ready
  }

  // ---- PV for the last subtile
  {
    int mp = (NSUB - 1) * SW;
#pragma unroll
    for (int mq = 0; mq < 4; ++mq) {
      float xw0 = xT[mq * 4 + 0][c1];
      float xw1 = xT[mq * 4 + 1][c1];
      float xw2 = xT[mq * 4 + 2][c1];
      float xw3 = xT[mq * 4 + 3][c1];
#pragma unroll
      for (int h = 0; h < NH; ++h) {
        float4 pb = *(const float4*)&Plds[h][mp + mq * 4];
        accy[h] += pb.x * xw0 + pb.y * xw1 + pb.z * xw2 + pb.w * xw3;
      }
    }
  }

  // partial denominators
  if (s2 && ((tid & 15) == 0))
    pd[((size_t)mt * B_ + b) * NH + (tid >> 4)] = pdacc;

  // ypart[mt][b][h][c] (coalesced per h)
  float* yp = ypart + ((size_t)mt * B_ + b) * NH * C_;
#pragma unroll
  for (int h = 0; h < NH; ++h) yp[h * C_ + c1] = accy[h];
}

// ---------------------------------------------------------------------------
// Kernel C (combine): y[b][h][c] = (sum_mt ypart) / (sum_mt pd)
__global__ __launch_bounds__(512) void combine_kernel(
    const float* __restrict__ pd, const float* __restrict__ ypart,
    float* __restrict__ y) {
  int bh = blockIdx.x;            // 0..191
  int b = bh / NH, h = bh % NH;
  int c = threadIdx.x;            // 0..511
  float denom = 0.f;
#pragma unroll
  for (int mt = 0; mt < MT_; ++mt)
    denom += pd[((size_t)mt * B_ + b) * NH + h];
  float s = 0.f;
#pragma unroll
  for (int mt = 0; mt < MT_; ++mt)
    s += ypart[(((size_t)mt * B_ + b) * NH + h) * C_ + c];
  y[((size_t)b * NH + h) * C_ + c] = s / denom;
}

// ---------------------------------------------------------------------------
// Kernel E: outT[b][t] = bv[t] + sum_c Wv[t,c] * y[b][t/64][c]
__global__ __launch_bounds__(256) void out_kernel(
    const float* __restrict__ Wv, const float* __restrict__ bv,
    const float* __restrict__ y, float* __restrict__ outT) {
  int o = blockIdx.x * 4 + (threadIdx.x >> 6);
  int lane = threadIdx.x & 63;
  int b = o / T_, t = o % T_;
  int h = t / DH;
  const float* wr = Wv + (size_t)t * C_;
  const float* yr = y + ((size_t)b * NH + h) * C_;
  float s = 0.f;
#pragma unroll
  for (int j = 0; j < 8; ++j) { int c = j * 64 + lane; s += wr[c] * yr[c]; }
  for (int off = 32; off; off >>= 1) s += __shfl_xor(s, off);
  if (lane == 0) outT[o] = s + bv[t];
}

// ---------------------------------------------------------------------------
// Kernel F (fused z+add): one warp per (b,c) plane.
__global__ __launch_bounds__(256) void zadd_kernel(
    const float* __restrict__ Wo, const float* __restrict__ bo,
    const float* __restrict__ outT, const float* __restrict__ cond,
    float* __restrict__ out) {
  int o = blockIdx.x * 4 + (threadIdx.x >> 6);  // o = b*C + c
  int lane = threadIdx.x & 63;
  int b = o / C_, c = o % C_;
  const float* wr = Wo + (size_t)c * T_;
  const float* orr = outT + (size_t)b * T_;
  float s = 0.f;
#pragma unroll
  for (int j = 0; j < 12; ++j) { int t = j * 64 + lane; s += wr[t] * orr[t]; }
  for (int off = 32; off; off >>= 1) s += __shfl_xor(s, off);
  float zv = s + bo[c];

  const nfloat4* cp = (const nfloat4*)(cond + (size_t)o * HW_);
  nfloat4* op = (nfloat4*)(out + (size_t)o * HW_);
#pragma unroll
  for (int j = 0; j < 16; ++j) {
    nfloat4 cv = __builtin_nontemporal_load(&cp[j * 64 + lane]);
    __builtin_nontemporal_store(cv + zv, &op[j * 64 + lane]);
  }
}

// ---------------------------------------------------------------------------
extern "C" void kernel_launch(void* const* d_in, const int* in_sizes, int n_in,
                              void* d_out, int out_size, void* d_ws, size_t ws_size,
                              hipStream_t stream) {
  const float* cond = (const float*)d_in[0];
  const float* t    = (const float*)d_in[1];
  const float* Wk   = (const float*)d_in[2];
  // bk (d_in[3]) unused: bias cancels in softmax
  const float* Wv   = (const float*)d_in[4];
  const float* bv   = (const float*)d_in[5];
  const float* Wo   = (const float*)d_in[6];
  const float* bo   = (const float*)d_in[7];
  float* out = (float*)d_out;
  float* ws  = (float*)d_ws;

  float* qkT   = ws;
  float* pd    = ws + 98304;
  float* ypart = ws + 104448;
  float* y     = ws + 3250176;
  float* outT  = ws + 3348480;

  hipLaunchKernelGGL(qk_kernel, dim3(B_ * NH), dim3(512), 0, stream,
                     t, Wk, qkT);
  hipLaunchKernelGGL(flash_kernel, dim3(MT_, B_), dim3(512), 0, stream,
                     cond, qkT, pd, ypart);
  hipLaunchKernelGGL(combine_kernel, dim3(B_ * NH), dim3(512), 0, stream,
                     pd, ypart, y);
  hipLaunchKernelGGL(out_kernel, dim3((B_ * T_) / 4), dim3(256), 0, stream,
                     Wv, bv, y, outT);
  hipLaunchKernelGGL(zadd_kernel, dim3((B_ * C_) / 4), dim3(256), 0, stream,
                     Wo, bo, outT, cond, out);
}

// Round 9
// 366.078 us; speedup vs baseline: 2.2172x; 1.1175x over previous
//
#include <hip/hip_runtime.h>
#include <math.h>

// Problem constants
#define B_   16
#define C_   512
#define HW_  4096
#define T_   768
#define NH   12
#define DH   64
#define MT_  32          // blocks per b; m-range per block = 128
#define MRANGE 128
#define SW   16          // subtile width (m)
#define NSUB 8           // MRANGE / SW
#define XSTR 516         // xT row stride

typedef float nfloat4 __attribute__((ext_vector_type(4)));

// Workspace layout (floats):
//   qkT   @ 0        [B][C][NH]        98304
//   pd    @ 98304    [MT][B][NH]       6144
//   ypart @ 104448   [MT][B][NH][C]    3145728
//   y     @ 3250176  [B][NH][C]        98304
//   outT  @ 3348480  [B][T]            12288

// ---------------------------------------------------------------------------
// Kernel A: qkT[b][c][h] = (1/8) * sum_dd t[b, h*64+dd] * Wk[h*64+dd, c]
__global__ __launch_bounds__(512) void qk_kernel(
    const float* __restrict__ t, const float* __restrict__ Wk,
    float* __restrict__ qkT) {
  int bh = blockIdx.x;
  int b = bh / NH, h = bh % NH;
  __shared__ float tl[DH];
  int tid = threadIdx.x;
  if (tid < DH) tl[tid] = t[b * T_ + h * DH + tid];
  __syncthreads();
  int c = tid;
  float acc = 0.f;
#pragma unroll
  for (int dd = 0; dd < DH; ++dd)
    acc += tl[dd] * Wk[(h * DH + dd) * C_ + c];
  qkT[((size_t)b * C_ + c) * NH + h] = acc * 0.125f;
}

// ---------------------------------------------------------------------------
// Kernel B (flash v5 = v4 with the spill fixed): block (mt,b) owns 128 m in
// 8 subtiles of 16.
// NOTE on __launch_bounds__: measured evidence (R7: (512,6)->40 VGPR,
// R8: (512,4)->64 VGPR) shows this toolchain treats arg2 as MIN BLOCKS/CU
// (CUDA semantics): cap = 2048 / (arg2*8 waves). Live set ~95 floats, so
// (512,2) -> 128-VGPR cap -> no spill, and LDS (70 KB) still limits us to
// the same 2 blocks/CU.
__global__ __launch_bounds__(512, 2) void flash_kernel(
    const float* __restrict__ x, const float* __restrict__ qkT,
    float* __restrict__ pd, float* __restrict__ ypart) {
  int mt = blockIdx.x;   // 0..31
  int b  = blockIdx.y;   // 0..15
  int tid = threadIdx.x; // 0..511

  __shared__ __align__(16) float qlds[NH][C_];      // 24576 B, [h][c]
  __shared__ __align__(16) float xT[SW][XSTR];      // 33024 B
  __shared__ __align__(16) float Plds[NH][MRANGE];  // 6144 B
  __shared__ __align__(16) float red[8][4][48];     // 6144 B
  // total 69.9 KB -> 2 blocks/CU

  // transpose-stage q once: qlds[h][c] = qkT[b][c][h]
  {
    const float* qsrc = qkT + (size_t)b * C_ * NH;
    for (int idx = tid; idx < C_ * NH; idx += 512) {
      int c = idx / NH, h = idx - c * NH;
      qlds[h][c] = qsrc[idx];
    }
  }

  const int m4 = tid & 3;    // m-slot: lane bits 0-1 -> 4 lanes x 16B = 64B runs
  const int cs = tid >> 2;   // 0..127, 4 consecutive c-rows each
  const int w  = tid >> 6;   // wave
  const int mbase = mt * MRANGE;
  const int c1 = tid;        // PV column
  const bool s2 = (tid < 192);

  float accy[NH];
#pragma unroll
  for (int h = 0; h < NH; ++h) accy[h] = 0.f;
  float pdacc = 0.f;

  const float* xp0 = x + ((size_t)b * C_ + cs * 4) * HW_ + mbase + m4 * 4;

  for (int ms = 0; ms < NSUB; ++ms) {
    // ---- 1. coalesced loads: 4 c-rows x float4
    float4 xv[4];
#pragma unroll
    for (int i = 0; i < 4; ++i)
      xv[i] = *(const float4*)(xp0 + (size_t)i * HW_ + ms * SW);

    // ---- 2. PV of previous subtile (overlaps load latency)
    if (ms > 0) {
      int mp = (ms - 1) * SW;
#pragma unroll
      for (int mq = 0; mq < 4; ++mq) {
        float xw0 = xT[mq * 4 + 0][c1];
        float xw1 = xT[mq * 4 + 1][c1];
        float xw2 = xT[mq * 4 + 2][c1];
        float xw3 = xT[mq * 4 + 3][c1];
#pragma unroll
        for (int h = 0; h < NH; ++h) {
          float4 pb = *(const float4*)&Plds[h][mp + mq * 4];
          accy[h] += pb.x * xw0 + pb.y * xw1 + pb.z * xw2 + pb.w * xw3;
        }
      }
    }
    __syncthreads();  // (a) xT writable; qlds staged (ms==0)

    // ---- 3. score partials + xT stage
    float sp[48];
#pragma unroll
    for (int j = 0; j < 48; ++j) sp[j] = 0.f;
#pragma unroll
    for (int i = 0; i < 4; ++i) {
      int c = cs * 4 + i;
      float4 v = xv[i];
#pragma unroll
      for (int h = 0; h < NH; ++h) {
        float qv = qlds[h][c];
        sp[h * 4 + 0] += qv * v.x;
        sp[h * 4 + 1] += qv * v.y;
        sp[h * 4 + 2] += qv * v.z;
        sp[h * 4 + 3] += qv * v.w;
      }
      xT[m4 * 4 + 0][c] = v.x;
      xT[m4 * 4 + 1][c] = v.y;
      xT[m4 * 4 + 2][c] = v.z;
      xT[m4 * 4 + 3][c] = v.w;
    }

    // ---- 4. in-wave reduce over 16 c-splits (lane bits 2-5)
#pragma unroll
    for (int j = 0; j < 48; ++j) {
      float v = sp[j];
      v += __shfl_xor(v, 4);
      v += __shfl_xor(v, 8);
      v += __shfl_xor(v, 16);
      v += __shfl_xor(v, 32);
      sp[j] = v;
    }
    if ((tid & 60) == 0) {  // lanes 0-3 of each wave (lane == m4)
#pragma unroll
      for (int q = 0; q < 12; ++q) {
        float4 t4;
        t4.x = sp[q * 4 + 0]; t4.y = sp[q * 4 + 1];
        t4.z = sp[q * 4 + 2]; t4.w = sp[q * 4 + 3];
        *(float4*)&red[w][m4][q * 4] = t4;
      }
    }
    __syncthreads();  // (b) red + xT ready

    // ---- 5. stage-2: sum 8 waves -> exp -> P; accumulate denominators
    if (s2) {
      int h = tid >> 4, j = (tid >> 2) & 3, mm = tid & 3;
      float s = 0.f;
#pragma unroll
      for (int w2 = 0; w2 < 8; ++w2) s += red[w2][mm][h * 4 + j];
      float p = __expf(s);
      Plds[h][ms * SW + mm * 4 + j] = p;
      float ps = p;
      ps += __shfl_xor(ps, 1);
      ps += __shfl_xor(ps, 2);
      ps += __shfl_xor(ps, 4);
      ps += __shfl_xor(ps, 8);
      pdacc += ps;  // full-subtile sum, valid on lanes with (tid&15)==0
    }
    __syncthreads();  // (c) P ready
  }

  // ---- PV for the last subtile
  {
    int mp = (NSUB - 1) * SW;
#pragma unroll
    for (int mq = 0; mq < 4; ++mq) {
      float xw0 = xT[mq * 4 + 0][c1];
      float xw1 = xT[mq * 4 + 1][c1];
      float xw2 = xT[mq * 4 + 2][c1];
      float xw3 = xT[mq * 4 + 3][c1];
#pragma unroll
      for (int h = 0; h < NH; ++h) {
        float4 pb = *(const float4*)&Plds[h][mp + mq * 4];
        accy[h] += pb.x * xw0 + pb.y * xw1 + pb.z * xw2 + pb.w * xw3;
      }
    }
  }

  // partial denominators
  if (s2 && ((tid & 15) == 0))
    pd[((size_t)mt * B_ + b) * NH + (tid >> 4)] = pdacc;

  // ypart[mt][b][h][c] (coalesced per h)
  float* yp = ypart + ((size_t)mt * B_ + b) * NH * C_;
#pragma unroll
  for (int h = 0; h < NH; ++h) yp[h * C_ + c1] = accy[h];
}

// ---------------------------------------------------------------------------
// Kernel C (combine): y[b][h][c] = (sum_mt ypart) / (sum_mt pd)
__global__ __launch_bounds__(512) void combine_kernel(
    const float* __restrict__ pd, const float* __restrict__ ypart,
    float* __restrict__ y) {
  int bh = blockIdx.x;            // 0..191
  int b = bh / NH, h = bh % NH;
  int c = threadIdx.x;            // 0..511
  float denom = 0.f;
#pragma unroll
  for (int mt = 0; mt < MT_; ++mt)
    denom += pd[((size_t)mt * B_ + b) * NH + h];
  float s = 0.f;
#pragma unroll
  for (int mt = 0; mt < MT_; ++mt)
    s += ypart[(((size_t)mt * B_ + b) * NH + h) * C_ + c];
  y[((size_t)b * NH + h) * C_ + c] = s / denom;
}

// ---------------------------------------------------------------------------
// Kernel E: outT[b][t] = bv[t] + sum_c Wv[t,c] * y[b][t/64][c]
__global__ __launch_bounds__(256) void out_kernel(
    const float* __restrict__ Wv, const float* __restrict__ bv,
    const float* __restrict__ y, float* __restrict__ outT) {
  int o = blockIdx.x * 4 + (threadIdx.x >> 6);
  int lane = threadIdx.x & 63;
  int b = o / T_, t = o % T_;
  int h = t / DH;
  const float* wr = Wv + (size_t)t * C_;
  const float* yr = y + ((size_t)b * NH + h) * C_;
  float s = 0.f;
#pragma unroll
  for (int j = 0; j < 8; ++j) { int c = j * 64 + lane; s += wr[c] * yr[c]; }
  for (int off = 32; off; off >>= 1) s += __shfl_xor(s, off);
  if (lane == 0) outT[o] = s + bv[t];
}

// ---------------------------------------------------------------------------
// Kernel F (fused z+add): one warp per (b,c) plane.
__global__ __launch_bounds__(256) void zadd_kernel(
    const float* __restrict__ Wo, const float* __restrict__ bo,
    const float* __restrict__ outT, const float* __restrict__ cond,
    float* __restrict__ out) {
  int o = blockIdx.x * 4 + (threadIdx.x >> 6);  // o = b*C + c
  int lane = threadIdx.x & 63;
  int b = o / C_, c = o % C_;
  const float* wr = Wo + (size_t)c * T_;
  const float* orr = outT + (size_t)b * T_;
  float s = 0.f;
#pragma unroll
  for (int j = 0; j < 12; ++j) { int t = j * 64 + lane; s += wr[t] * orr[t]; }
  for (int off = 32; off; off >>= 1) s += __shfl_xor(s, off);
  float zv = s + bo[c];

  const nfloat4* cp = (const nfloat4*)(cond + (size_t)o * HW_);
  nfloat4* op = (nfloat4*)(out + (size_t)o * HW_);
#pragma unroll
  for (int j = 0; j < 16; ++j) {
    nfloat4 cv = __builtin_nontemporal_load(&cp[j * 64 + lane]);
    __builtin_nontemporal_store(cv + zv, &op[j * 64 + lane]);
  }
}

// ---------------------------------------------------------------------------
extern "C" void kernel_launch(void* const* d_in, const int* in_sizes, int n_in,
                              void* d_out, int out_size, void* d_ws, size_t ws_size,
                              hipStream_t stream) {
  const float* cond = (const float*)d_in[0];
  const float* t    = (const float*)d_in[1];
  const float* Wk   = (const float*)d_in[2];
  // bk (d_in[3]) unused: bias cancels in softmax
  const float* Wv   = (const float*)d_in[4];
  const float* bv   = (const float*)d_in[5];
  const float* Wo   = (const float*)d_in[6];
  const float* bo   = (const float*)d_in[7];
  float* out = (float*)d_out;
  float* ws  = (float*)d_ws;

  float* qkT   = ws;
  float* pd    = ws + 98304;
  float* ypart = ws + 104448;
  float* y     = ws + 3250176;
  float* outT  = ws + 3348480;

  hipLaunchKernelGGL(qk_kernel, dim3(B_ * NH), dim3(512), 0, stream,
                     t, Wk, qkT);
  hipLaunchKernelGGL(flash_kernel, dim3(MT_, B_), dim3(512), 0, stream,
                     cond, qkT, pd, ypart);
  hipLaunchKernelGGL(combine_kernel, dim3(B_ * NH), dim3(512), 0, stream,
                     pd, ypart, y);
  hipLaunchKernelGGL(out_kernel, dim3((B_ * T_) / 4), dim3(256), 0, stream,
                     Wv, bv, y, outT);
  hipLaunchKernelGGL(zadd_kernel, dim3((B_ * C_) / 4), dim3(256), 0, stream,
                     Wo, bo, outT, cond, out);
}

// Round 10
// 282.497 us; speedup vs baseline: 2.8732x; 1.2959x over previous
//
#include <hip/hip_runtime.h>
#include <math.h>

// Problem constants
#define B_   16
#define C_   512
#define HW_  4096
#define T_   768
#define NH   12
#define DH   64
#define MT_  32          // blocks per b; m-range per block = 128 (4 subtiles x 32)

typedef float nfloat4 __attribute__((ext_vector_type(4)));
typedef short bf16x8 __attribute__((ext_vector_type(8)));
typedef float f32x4  __attribute__((ext_vector_type(4)));

// fp32 -> bf16 (RNE)
__device__ __forceinline__ unsigned short f2bf(float f) {
  union { float f; unsigned u; } v; v.f = f;
  unsigned r = v.u + 0x7FFFu + ((v.u >> 16) & 1u);
  return (unsigned short)(r >> 16);
}

// Workspace layout (floats):
//   qT    @ 0        [B][16][C] bf16   (65536 float-slots; h rows 12-15 zero)
//   pd    @ 65536    [MT][B][NH]       6144
//   ypart @ 71680    [MT][B][NH][C]    3145728
//   y     @ 3217408  [B][NH][C]        98304
//   outT  @ 3315712  [B][T]            12288

// ---------------------------------------------------------------------------
// Kernel A: qT[b][h][c] = bf16( (1/8) * sum_dd t[b,h*64+dd] * Wk[h*64+dd,c] )
// h rows 12..15 zeroed (MFMA fragment rows must be valid memory).
__global__ __launch_bounds__(512) void qk_kernel(
    const float* __restrict__ t, const float* __restrict__ Wk,
    unsigned short* __restrict__ qT) {
  int o = blockIdx.x;           // 0..255
  int b = o >> 4, h = o & 15;
  int tid = threadIdx.x;        // = c
  __shared__ float tl[DH];
  if (h < NH && tid < DH) tl[tid] = t[b * T_ + h * DH + tid];
  __syncthreads();
  float acc = 0.f;
  if (h < NH) {
#pragma unroll
    for (int dd = 0; dd < DH; ++dd)
      acc += tl[dd] * Wk[(h * DH + dd) * C_ + tid];
    acc *= 0.125f;
  }
  qT[((size_t)(b * 16 + h)) * C_ + tid] = (h < NH) ? f2bf(acc) : (unsigned short)0;
}

// ---------------------------------------------------------------------------
// Kernel B (flash v7, MFMA): block (mt,b) owns 128 m in 4 subtiles of 32.
// Score: S[16h x 16m] = q[16h x 512c] . x[512c x 16m], 16 k-steps of 32,
//   A-frag from global qT[b][h][c] (k-contig), B-frag from xT[m][c] LDS.
// PV:    y[16h x 16c-tile] += P[16h x 32m] . x[32m x 16c], 1 k-step,
//   A-frag from Plds[h][m], B-frag from xtile[c][m].
// A/B k-slots use identical lane mappings -> k-interleave cancels exactly.
// C/D: col = lane&15, row = (lane>>4)*4 + reg (guide-verified).
__global__ __launch_bounds__(512) void flash_kernel(
    const float* __restrict__ x, const unsigned short* __restrict__ qT,
    float* __restrict__ pd, float* __restrict__ ypart) {
  int mt = blockIdx.x;   // 0..31
  int b  = blockIdx.y;   // 0..15
  int tid = threadIdx.x; // 0..511
  int lane = tid & 63, w = tid >> 6;
  int l15 = lane & 15, l4 = lane >> 4;
  int mq = tid & 7, cg = tid >> 3;   // staging: mq = float4-slot (4m), cg = c-group (8c)

  __shared__ unsigned short xtile[C_][40];   // [c][m] bf16, stride 40 (80B, 16B-aligned, reads 2-way)
  __shared__ unsigned short xT[32][520];     // [m][c] bf16, stride 520 (1040B, reads 2-way)
  __shared__ unsigned short Plds[16][56];    // [h][m] bf16, stride 56 (112B, reads 2-way)
  __shared__ f32x4 red[4][64];               // score C-partials
  // total 78.3 KB -> 2 blocks/CU

  f32x4 acc[4];                              // PV accumulators: wave's 4 c-tiles
#pragma unroll
  for (int i = 0; i < 4; ++i) acc[i] = (f32x4){0.f, 0.f, 0.f, 0.f};
  f32x4 pdacc = (f32x4){0.f, 0.f, 0.f, 0.f}; // wave0 only

  const float* xb = x + ((size_t)b * C_ + cg * 8) * HW_ + mt * 128 + mq * 4;
  const unsigned short* qrow = qT + ((size_t)(b * 16 + l15)) * C_ + l4 * 8;

  for (int ms = 0; ms < 4; ++ms) {
    // ---- 1. global loads for this subtile (coalesced: 8 c-rows x float4)
    float4 xv[8];
#pragma unroll
    for (int i = 0; i < 8; ++i)
      xv[i] = *(const float4*)(xb + (size_t)i * HW_ + ms * 32);

    // ---- 2. PV of previous subtile (K=32 m) — overlaps load latency
    if (ms > 0) {
      bf16x8 pa = *(const bf16x8*)&Plds[l15][l4 * 8];
#pragma unroll
      for (int ct = 0; ct < 4; ++ct) {
        bf16x8 xf = *(const bf16x8*)&xtile[(w * 4 + ct) * 16 + l15][l4 * 8];
        acc[ct] = __builtin_amdgcn_mfma_f32_16x16x32_bf16(pa, xf, acc[ct], 0, 0, 0);
      }
    }
    __syncthreads();  // (a) PV done -> xtile/xT writable

    // ---- 3. stage bf16: xtile[c][m] (uint2 = 4 bf16) + xT[m][c] (scatter)
#pragma unroll
    for (int i = 0; i < 8; ++i) {
      unsigned short b0 = f2bf(xv[i].x), b1 = f2bf(xv[i].y);
      unsigned short b2 = f2bf(xv[i].z), b3 = f2bf(xv[i].w);
      uint2 pk;
      pk.x = (unsigned)b0 | ((unsigned)b1 << 16);
      pk.y = (unsigned)b2 | ((unsigned)b3 << 16);
      *(uint2*)&xtile[cg * 8 + i][mq * 4] = pk;
      xT[mq * 4 + 0][cg * 8 + i] = b0;
      xT[mq * 4 + 1][cg * 8 + i] = b1;
      xT[mq * 4 + 2][cg * 8 + i] = b2;
      xT[mq * 4 + 3][cg * 8 + i] = b3;
    }
    __syncthreads();  // (b) staged

    // ---- 4. score half0 (m 0-15): waves 0-3, 4 k-steps each
    if (w < 4) {
      f32x4 c4 = (f32x4){0.f, 0.f, 0.f, 0.f};
#pragma unroll
      for (int kk = 0; kk < 4; ++kk) {
        int c0 = (w * 4 + kk) * 32;
        bf16x8 a = *(const bf16x8*)(qrow + c0);
        bf16x8 bb = *(const bf16x8*)&xT[l15][c0 + l4 * 8];
        c4 = __builtin_amdgcn_mfma_f32_16x16x32_bf16(a, bb, c4, 0, 0, 0);
      }
      red[w][lane] = c4;
    }
    __syncthreads();  // (c)

    // ---- 5. exp half0 (wave0): S -> P -> Plds[.][0-15]; pd partials
    if (w == 0) {
      f32x4 s = red[0][lane];
      s += red[1][lane]; s += red[2][lane]; s += red[3][lane];
#pragma unroll
      for (int r = 0; r < 4; ++r) {
        float p = __expf(s[r]);
        Plds[l4 * 4 + r][l15] = f2bf(p);
        float v = p;
        v += __shfl_xor(v, 1); v += __shfl_xor(v, 2);
        v += __shfl_xor(v, 4); v += __shfl_xor(v, 8);
        pdacc[r] += v;
      }
    }
    __syncthreads();  // (d) red reusable

    // ---- 6. score half1 (m 16-31): waves 4-7
    if (w >= 4) {
      int ww = w - 4;
      f32x4 c4 = (f32x4){0.f, 0.f, 0.f, 0.f};
#pragma unroll
      for (int kk = 0; kk < 4; ++kk) {
        int c0 = (ww * 4 + kk) * 32;
        bf16x8 a = *(const bf16x8*)(qrow + c0);
        bf16x8 bb = *(const bf16x8*)&xT[16 + l15][c0 + l4 * 8];
        c4 = __builtin_amdgcn_mfma_f32_16x16x32_bf16(a, bb, c4, 0, 0, 0);
      }
      red[ww][lane] = c4;
    }
    __syncthreads();  // (e)

    // ---- 7. exp half1 (wave0)
    if (w == 0) {
      f32x4 s = red[0][lane];
      s += red[1][lane]; s += red[2][lane]; s += red[3][lane];
#pragma unroll
      for (int r = 0; r < 4; ++r) {
        float p = __expf(s[r]);
        Plds[l4 * 4 + r][16 + l15] = f2bf(p);
        float v = p;
        v += __shfl_xor(v, 1); v += __shfl_xor(v, 2);
        v += __shfl_xor(v, 4); v += __shfl_xor(v, 8);
        pdacc[r] += v;
      }
    }
    __syncthreads();  // (f) Plds complete -> next PV
  }

  // ---- PV for the last subtile
  {
    bf16x8 pa = *(const bf16x8*)&Plds[l15][l4 * 8];
#pragma unroll
    for (int ct = 0; ct < 4; ++ct) {
      bf16x8 xf = *(const bf16x8*)&xtile[(w * 4 + ct) * 16 + l15][l4 * 8];
      acc[ct] = __builtin_amdgcn_mfma_f32_16x16x32_bf16(pa, xf, acc[ct], 0, 0, 0);
    }
  }

  // ---- pd store (wave0; lanes l15==0 hold the m-sums; h = l4*4+r < 12)
  if (w == 0 && l15 == 0 && l4 < 3) {
#pragma unroll
    for (int r = 0; r < 4; ++r)
      pd[((size_t)mt * B_ + b) * NH + (l4 * 4 + r)] = pdacc[r];
  }

  // ---- ypart store: lane holds y[h = l4*4+r][c = (w*4+ct)*16 + l15]
  if (l4 < 3) {
#pragma unroll
    for (int ct = 0; ct < 4; ++ct)
#pragma unroll
      for (int r = 0; r < 4; ++r) {
        int h = l4 * 4 + r;
        ypart[(((size_t)mt * B_ + b) * NH + h) * C_ + (w * 4 + ct) * 16 + l15] =
            acc[ct][r];
      }
  }
}

// ---------------------------------------------------------------------------
// Kernel C (combine): y[b][h][c] = (sum_mt ypart) / (sum_mt pd)
__global__ __launch_bounds__(512) void combine_kernel(
    const float* __restrict__ pd, const float* __restrict__ ypart,
    float* __restrict__ y) {
  int bh = blockIdx.x;            // 0..191
  int b = bh / NH, h = bh % NH;
  int c = threadIdx.x;            // 0..511
  float denom = 0.f;
#pragma unroll
  for (int mt = 0; mt < MT_; ++mt)
    denom += pd[((size_t)mt * B_ + b) * NH + h];
  float s = 0.f;
#pragma unroll
  for (int mt = 0; mt < MT_; ++mt)
    s += ypart[(((size_t)mt * B_ + b) * NH + h) * C_ + c];
  y[((size_t)b * NH + h) * C_ + c] = s / denom;
}

// ---------------------------------------------------------------------------
// Kernel E: outT[b][t] = bv[t] + sum_c Wv[t,c] * y[b][t/64][c]
__global__ __launch_bounds__(256) void out_kernel(
    const float* __restrict__ Wv, const float* __restrict__ bv,
    const float* __restrict__ y, float* __restrict__ outT) {
  int o = blockIdx.x * 4 + (threadIdx.x >> 6);
  int lane = threadIdx.x & 63;
  int b = o / T_, t = o % T_;
  int h = t / DH;
  const float* wr = Wv + (size_t)t * C_;
  const float* yr = y + ((size_t)b * NH + h) * C_;
  float s = 0.f;
#pragma unroll
  for (int j = 0; j < 8; ++j) { int c = j * 64 + lane; s += wr[c] * yr[c]; }
  for (int off = 32; off; off >>= 1) s += __shfl_xor(s, off);
  if (lane == 0) outT[o] = s + bv[t];
}

// ---------------------------------------------------------------------------
// Kernel F (fused z+add): one warp per (b,c) plane.
__global__ __launch_bounds__(256) void zadd_kernel(
    const float* __restrict__ Wo, const float* __restrict__ bo,
    const float* __restrict__ outT, const float* __restrict__ cond,
    float* __restrict__ out) {
  int o = blockIdx.x * 4 + (threadIdx.x >> 6);  // o = b*C + c
  int lane = threadIdx.x & 63;
  int b = o / C_, c = o % C_;
  const float* wr = Wo + (size_t)c * T_;
  const float* orr = outT + (size_t)b * T_;
  float s = 0.f;
#pragma unroll
  for (int j = 0; j < 12; ++j) { int t = j * 64 + lane; s += wr[t] * orr[t]; }
  for (int off = 32; off; off >>= 1) s += __shfl_xor(s, off);
  float zv = s + bo[c];

  const nfloat4* cp = (const nfloat4*)(cond + (size_t)o * HW_);
  nfloat4* op = (nfloat4*)(out + (size_t)o * HW_);
#pragma unroll
  for (int j = 0; j < 16; ++j) {
    nfloat4 cv = __builtin_nontemporal_load(&cp[j * 64 + lane]);
    __builtin_nontemporal_store(cv + zv, &op[j * 64 + lane]);
  }
}

// ---------------------------------------------------------------------------
extern "C" void kernel_launch(void* const* d_in, const int* in_sizes, int n_in,
                              void* d_out, int out_size, void* d_ws, size_t ws_size,
                              hipStream_t stream) {
  const float* cond = (const float*)d_in[0];
  const float* t    = (const float*)d_in[1];
  const float* Wk   = (const float*)d_in[2];
  // bk (d_in[3]) unused: bias cancels in softmax
  const float* Wv   = (const float*)d_in[4];
  const float* bv   = (const float*)d_in[5];
  const float* Wo   = (const float*)d_in[6];
  const float* bo   = (const float*)d_in[7];
  float* out = (float*)d_out;
  float* ws  = (float*)d_ws;

  unsigned short* qT = (unsigned short*)ws;      // [B][16][C] bf16
  float* pd    = ws + 65536;
  float* ypart = ws + 71680;
  float* y     = ws + 3217408;
  float* outT  = ws + 3315712;

  hipLaunchKernelGGL(qk_kernel, dim3(B_ * 16), dim3(512), 0, stream,
                     t, Wk, qT);
  hipLaunchKernelGGL(flash_kernel, dim3(MT_, B_), dim3(512), 0, stream,
                     cond, qT, pd, ypart);
  hipLaunchKernelGGL(combine_kernel, dim3(B_ * NH), dim3(512), 0, stream,
                     pd, ypart, y);
  hipLaunchKernelGGL(out_kernel, dim3((B_ * T_) / 4), dim3(256), 0, stream,
                     Wv, bv, y, outT);
  hipLaunchKernelGGL(zadd_kernel, dim3((B_ * C_) / 4), dim3(256), 0, stream,
                     Wo, bo, outT, cond, out);
}